// Round 6
// baseline (674.570 us; speedup 1.0000x reference)
//
#include <hip/hip_runtime.h>

#define NPTS 8192
#define NCH 8
#define STRIDE 6144
#define TOTAL 51200
#define FADE 1228
#define SEG 32
#define SEGLEN 256   // NPTS / SEG
#define JB 4         // j's per thread in argmin
#define NBLK 256u

// ---------------------------------------------------------------------------
// Manual grid barrier: single-use slots, device-scope fences around a
// relaxed agent-scope counter. Blocks are all co-resident (256 blocks,
// 31 KB LDS, launch_bounds(256,1) => >= 1 block/CU capacity chip-wide).
__device__ inline void gsync(unsigned* bar, int slot) {
    __syncthreads();
    if (threadIdx.x == 0) {
        __threadfence();   // release: push this block's stores to device scope
        __hip_atomic_fetch_add(&bar[slot], 1u, __ATOMIC_RELAXED, __HIP_MEMORY_SCOPE_AGENT);
        while (__hip_atomic_load(&bar[slot], __ATOMIC_RELAXED, __HIP_MEMORY_SCOPE_AGENT) < NBLK) { }
        __threadfence();   // acquire: invalidate stale lines before later plain loads
    }
    __syncthreads();
}

// Single persistent kernel: setup -> 7x(argmin -> resolve -> smoother+scatter) -> merge.
// All fp chains instruction-identical to the passing round-4 kernels.
__global__ __launch_bounds__(256, 1) void k_fusion(
        const float* __restrict__ chunks,
        const float* __restrict__ bw1, const float* __restrict__ bb1,
        const float* __restrict__ bw2, const float* __restrict__ bb2,
        const float* __restrict__ bw3, const float* __restrict__ bb3,
        const float* __restrict__ pw1, const float* __restrict__ pb1,
        const float* __restrict__ pw2, const float* __restrict__ pb2,
        const float* __restrict__ pw3, const float* __restrict__ pb3,
        unsigned* bar,
        unsigned long long* __restrict__ packed_all,
        float* __restrict__ fin, float* __restrict__ fused,
        int* __restrict__ mi, int* __restrict__ jmax_all,
        float* __restrict__ out) {
#pragma clang fp contract(off)
    // LDS union: phase A 1024 f; phase B 780 f; phase C 7780 f (31.1 KB)
    __shared__ __align__(16) float smem[7780];
    int tid = threadIdx.x;
    int bid = blockIdx.x;
    int gidx = bid * 256 + tid;                       // 0..65535
    int slot = 0;

    // ---------------- setup: fin = chunks, jmax = -1, packed = ~0 ----------------
    for (int i = gidx; i < NCH * NPTS * 3; i += 65536) fin[i] = chunks[i];
    if (gidx < (NCH - 1) * NPTS) {
        jmax_all[gidx] = -1;
        packed_all[gidx] = ~0ull;
    }
    gsync(bar, slot++);

    for (int pair = 1; pair < NCH; ++pair) {
        const float* C = chunks + pair * NPTS * 3;
        float* P  = fin + (pair - 1) * NPTS * 3;
        float* Pn = fin + pair * NPTS * 3;
        unsigned long long* packed = packed_all + (pair - 1) * NPTS;
        int* jmax = jmax_all + (pair - 1) * NPTS;

        // ---------------- phase A: brute-force argmin partial ----------------
        {
            float4* sh = (float4*)smem;
            int seg = bid & 31, jblk = bid >> 5;      // 32 segments x 8 j-blocks
            int k0 = seg * SEGLEN;
            {
                int k = k0 + tid;
                float x = C[k * 3 + 0], y = C[k * 3 + 1], z = C[k * 3 + 2];
                float cc = (x * x + y * y) + z * z;
                sh[tid] = make_float4(x, y, z, cc);
            }
            __syncthreads();
            int j0 = jblk * 1024 + tid * JB;
            const float4* Pv = (const float4*)(P + j0 * 3);
            float4 a = Pv[0], b = Pv[1], c4 = Pv[2];
            float p0[JB] = {a.x, a.w, b.z, c4.y};
            float p1[JB] = {a.y, b.x, b.w, c4.z};
            float p2[JB] = {a.z, b.y, c4.x, c4.w};
            float pp[JB], best[JB];
            int bt[JB];
#pragma unroll
            for (int i = 0; i < JB; ++i) {
                pp[i] = (p0[i] * p0[i] + p1[i] * p1[i]) + p2[i] * p2[i];
                best[i] = 3.4e38f;
                bt[i] = 0;
            }
#pragma unroll 4
            for (int t = 0; t < SEGLEN; ++t) {
                float4 f = sh[t];
#pragma unroll
                for (int i = 0; i < JB; ++i) {
                    float g = __builtin_fmaf(p2[i], f.z, __builtin_fmaf(p1[i], f.y, p0[i] * f.x));
                    float sadd = pp[i] + f.w;
                    float d = __builtin_fmaf(-2.0f, g, sadd);
                    if (d < best[i]) { best[i] = d; bt[i] = t; }   // strict <
                }
            }
#pragma unroll
            for (int i = 0; i < JB; ++i) {
                unsigned ud = __float_as_uint(best[i]);
                if (ud == 0x80000000u) ud = 0u;                         // -0 -> +0
                ud = (ud & 0x80000000u) ? ~ud : (ud | 0x80000000u);     // order-preserving
                unsigned long long pk = ((unsigned long long)ud << 32)
                                      | (unsigned long long)(unsigned)(k0 + bt[i]);
                atomicMin(&packed[j0 + i], pk);
            }
        }
        gsync(bar, slot++);

        // ---------------- phase B: resolve (MLP + fused + jmax) ----------------
        if (bid < 32) {
            float* W = smem;
            for (int i = tid; i < 780; i += 256) {
                float v;
                if (i < 192) v = pw1[i];
                else if (i < 224) v = pb1[i - 192];
                else if (i < 736) v = pw2[i - 224];
                else if (i < 752) v = pb2[i - 736];
                else if (i < 768) v = pw3[i - 752];
                else v = pb3[0];
                W[i] = v;
            }
            __syncthreads();

            int j = bid * 256 + tid;
            int m = (int)(unsigned)(packed[j] & 0xFFFFFFFFull);
            mi[j] = m;
            float x6[6];
            x6[0] = P[j * 3 + 0]; x6[1] = P[j * 3 + 1]; x6[2] = P[j * 3 + 2];
            x6[3] = C[m * 3 + 0]; x6[4] = C[m * 3 + 1]; x6[5] = C[m * 3 + 2];

            float h1[32];
#pragma unroll
            for (int o = 0; o < 32; ++o) {
                float acc = 0.0f;
#pragma unroll
                for (int ci = 0; ci < 6; ++ci) acc = __builtin_fmaf(x6[ci], W[o * 6 + ci], acc);
                h1[o] = fmaxf(acc + W[192 + o], 0.0f);
            }
            float h2[16];
#pragma unroll
            for (int o = 0; o < 16; ++o) {
                float acc = 0.0f;
#pragma unroll
                for (int ci = 0; ci < 32; ++ci) acc = __builtin_fmaf(h1[ci], W[224 + o * 32 + ci], acc);
                h2[o] = fmaxf(acc + W[736 + o], 0.0f);
            }
            float acc = 0.0f;
#pragma unroll
            for (int ci = 0; ci < 16; ++ci) acc = __builtin_fmaf(h2[ci], W[752 + ci], acc);
            float z = acc + W[768];
            float w = 1.0f / (1.0f + expf(-z));
            float omw = 1.0f - w;
#pragma unroll
            for (int e = 0; e < 3; ++e) {
                float t1 = w * x6[e];
                float t2 = omw * x6[3 + e];
                fused[e * NPTS + j] = t1 + t2;
            }
            // wave-level dedupe: highest-j lane per distinct m issues the atomic
            int lane = tid & 63;
            bool issue = true;
            for (int s = 1; s < 64; ++s) {
                int om = __shfl_down(m, s);
                if (lane + s < 64 && om == m) issue = false;
            }
            if (issue) atomicMax(&jmax[m], j);
        }
        gsync(bar, slot++);

        // ---------------- phase C: smoother + fused scatter ----------------
        {
            float* W2 = smem;             // 5120
            float* B2 = smem + 5120;      // 32
            float* F  = smem + 5152;      // 3*44
            float* H1 = smem + 5284;      // 32*41
            float* H2 = smem + 6596;      // 32*37
            int BASE = bid * 32;

            for (int li = tid; li < 132; li += 256) {
                int c = li / 44, i = li % 44;
                int t = BASE - 6 + i;
                F[c * 44 + i] = (t >= 0 && t < NPTS) ? fused[c * NPTS + t] : 0.0f;
            }
            for (int li = tid; li < 1280; li += 256) {
                float4 v = ((const float4*)bw2)[li];
                int base = li * 4;
#pragma unroll
                for (int u = 0; u < 4; ++u) {
                    int idx = base + u;              // (co*32+ci)*5+k
                    int co = idx / 160;
                    int r = idx - co * 160;
                    int ci = r / 5;
                    int k = r - ci * 5;
                    W2[(ci * 5 + k) * 32 + co] = (&v.x)[u];
                }
            }
            if (tid < 32) B2[tid] = bb2[tid];
            __syncthreads();

            {   // conv1 -> H1 on [BASE-4, BASE+36)
                int co = tid >> 3, pg = tid & 7;
                float wr[15];
#pragma unroll
                for (int q = 0; q < 15; ++q) wr[q] = bw1[co * 15 + q];
                float bias = bb1[co];
#pragma unroll
                for (int s = 0; s < 5; ++s) {
                    int i = pg * 5 + s;
                    int t = BASE - 4 + i;
                    float acc = 0.0f;
#pragma unroll
                    for (int k = 0; k < 5; ++k)
#pragma unroll
                        for (int ci = 0; ci < 3; ++ci)
                            acc = __builtin_fmaf(F[ci * 44 + i + k], wr[ci * 5 + k], acc);
                    H1[co * 41 + i] = (t >= 0 && t < NPTS) ? fmaxf(acc + bias, 0.0f) : 0.0f;
                }
            }
            __syncthreads();

            {   // conv2 -> H2 on [BASE-2, BASE+34)
                int cq = tid & 7, pq = tid >> 3;
                if (pq < 18) {
                    int i2 = pq * 2;
                    int co0 = cq * 4;
                    float acc00 = 0.f, acc01 = 0.f, acc02 = 0.f, acc03 = 0.f;
                    float acc10 = 0.f, acc11 = 0.f, acc12 = 0.f, acc13 = 0.f;
                    for (int k = 0; k < 5; ++k) {
#pragma unroll
                        for (int ci = 0; ci < 32; ++ci) {
                            float in0 = H1[ci * 41 + i2 + k];
                            float in1 = H1[ci * 41 + i2 + k + 1];
                            const float4 wv = *(const float4*)&W2[(ci * 5 + k) * 32 + co0];
                            acc00 = __builtin_fmaf(in0, wv.x, acc00);
                            acc01 = __builtin_fmaf(in0, wv.y, acc01);
                            acc02 = __builtin_fmaf(in0, wv.z, acc02);
                            acc03 = __builtin_fmaf(in0, wv.w, acc03);
                            acc10 = __builtin_fmaf(in1, wv.x, acc10);
                            acc11 = __builtin_fmaf(in1, wv.y, acc11);
                            acc12 = __builtin_fmaf(in1, wv.z, acc12);
                            acc13 = __builtin_fmaf(in1, wv.w, acc13);
                        }
                    }
                    int t0 = BASE - 2 + i2, t1 = t0 + 1;
                    bool ok0 = (t0 >= 0 && t0 < NPTS), ok1 = (t1 >= 0 && t1 < NPTS);
                    H2[(co0 + 0) * 37 + i2]     = ok0 ? fmaxf(acc00 + B2[co0 + 0], 0.0f) : 0.0f;
                    H2[(co0 + 1) * 37 + i2]     = ok0 ? fmaxf(acc01 + B2[co0 + 1], 0.0f) : 0.0f;
                    H2[(co0 + 2) * 37 + i2]     = ok0 ? fmaxf(acc02 + B2[co0 + 2], 0.0f) : 0.0f;
                    H2[(co0 + 3) * 37 + i2]     = ok0 ? fmaxf(acc03 + B2[co0 + 3], 0.0f) : 0.0f;
                    H2[(co0 + 0) * 37 + i2 + 1] = ok1 ? fmaxf(acc10 + B2[co0 + 0], 0.0f) : 0.0f;
                    H2[(co0 + 1) * 37 + i2 + 1] = ok1 ? fmaxf(acc11 + B2[co0 + 1], 0.0f) : 0.0f;
                    H2[(co0 + 2) * 37 + i2 + 1] = ok1 ? fmaxf(acc12 + B2[co0 + 2], 0.0f) : 0.0f;
                    H2[(co0 + 3) * 37 + i2 + 1] = ok1 ? fmaxf(acc13 + B2[co0 + 3], 0.0f) : 0.0f;
                }
            }
            __syncthreads();

            if (tid < 96) {   // conv3 -> sm (overwrites P) + scatter winners -> Pn
                int co = tid >> 5, p = tid & 31;
                float wr[160];
                const float4* w3v = (const float4*)(bw3 + co * 160);
#pragma unroll
                for (int q = 0; q < 40; ++q) {
                    float4 v = w3v[q];
                    wr[q * 4 + 0] = v.x; wr[q * 4 + 1] = v.y;
                    wr[q * 4 + 2] = v.z; wr[q * 4 + 3] = v.w;
                }
                float acc = 0.0f;
#pragma unroll
                for (int k = 0; k < 5; ++k)
#pragma unroll
                    for (int ci = 0; ci < 32; ++ci)
                        acc = __builtin_fmaf(H2[ci * 37 + p + k], wr[ci * 5 + k], acc);
                float val = acc + bb3[co];
                int jj = BASE + p;
                P[jj * 3 + co] = val;
                int kk = mi[jj];
                if (jmax[kk] == jj) Pn[kk * 3 + co] = val;   // unique winner per kk
            }
        }
        gsync(bar, slot++);
    }

    // ---------------- merge ----------------
    {
        int pos = gidx;
        if (pos < TOTAL) {
            int imax = pos / STRIDE; if (imax > NCH - 1) imax = NCH - 1;
            int imin = (pos >= NPTS) ? ((pos - NPTS) / STRIDE + 1) : 0;
            float a0 = 0.0f, a1 = 0.0f, a2 = 0.0f, wsum = 0.0f;
            const float kstep = 0.9f / 1227.0f;
            for (int i = imin; i <= imax; ++i) {
                int t = pos - i * STRIDE;
                float cw;
                if (t < FADE)                cw = 0.1f + (float)t * kstep;
                else if (t >= NPTS - FADE)   cw = 1.0f - (float)(t - (NPTS - FADE)) * kstep;
                else                         cw = 1.0f;
                const float* v = fin + (i * NPTS + t) * 3;
                a0 += cw * v[0];
                a1 += cw * v[1];
                a2 += cw * v[2];
                wsum += cw;
            }
            float wm = fmaxf(wsum, 1e-8f);
            out[pos * 3 + 0] = a0 / wm;
            out[pos * 3 + 1] = a1 / wm;
            out[pos * 3 + 2] = a2 / wm;
        }
    }
}

// ---------------------------------------------------------------------------
extern "C" void kernel_launch(void* const* d_in, const int* in_sizes, int n_in,
                              void* d_out, int out_size, void* d_ws, size_t ws_size,
                              hipStream_t stream) {
    const float* chunks = (const float*)d_in[0];
    const float* bs_w1 = (const float*)d_in[1];
    const float* bs_b1 = (const float*)d_in[2];
    const float* bs_w2 = (const float*)d_in[3];
    const float* bs_b2 = (const float*)d_in[4];
    const float* bs_w3 = (const float*)d_in[5];
    const float* bs_b3 = (const float*)d_in[6];
    const float* wp_w1 = (const float*)d_in[7];
    const float* wp_b1 = (const float*)d_in[8];
    const float* wp_w2 = (const float*)d_in[9];
    const float* wp_b2 = (const float*)d_in[10];
    const float* wp_w3 = (const float*)d_in[11];
    const float* wp_b3 = (const float*)d_in[12];

    unsigned* bar = (unsigned*)d_ws;                              // 32 u32 (128 B)
    unsigned long long* packed_all = (unsigned long long*)((char*)d_ws + 128); // 7*8192 u64
    float* fin      = (float*)(packed_all + (NCH - 1) * NPTS);    // 196608 f32
    float* fused    = fin + NCH * NPTS * 3;                       // 24576 f32
    int*   mi       = (int*)(fused + 3 * NPTS);                   // 8192 i32
    int*   jmax_all = mi + NPTS;                                  // 57344 i32
    float* out      = (float*)d_out;

    hipMemsetAsync(bar, 0, 128, stream);   // zero barrier slots (capture-safe)

    k_fusion<<<256, 256, 0, stream>>>(chunks,
        bs_w1, bs_b1, bs_w2, bs_b2, bs_w3, bs_b3,
        wp_w1, wp_b1, wp_w2, wp_b2, wp_w3, wp_b3,
        bar, packed_all, fin, fused, mi, jmax_all, out);
}

// Round 7
// 457.258 us; speedup vs baseline: 1.4752x; 1.4752x over previous
//
#include <hip/hip_runtime.h>

#define NPTS 8192
#define NCH 8
#define STRIDE 6144
#define TOTAL 51200
#define FADE 1228
#define NBLK 256u

// ---------------------------------------------------------------------------
// Agent-scope relaxed accessors: lower to sc0/sc1 global ops serviced at the
// device coherence point (bypass non-coherent per-XCD L2). All cross-block
// data uses these; read-only inputs use normal cached loads.
__device__ __forceinline__ float aload(const float* p) {
    return __hip_atomic_load(p, __ATOMIC_RELAXED, __HIP_MEMORY_SCOPE_AGENT);
}
__device__ __forceinline__ void astore(float* p, float v) {
    __hip_atomic_store(p, v, __ATOMIC_RELAXED, __HIP_MEMORY_SCOPE_AGENT);
}
__device__ __forceinline__ int aloadi(const int* p) {
    return __hip_atomic_load(p, __ATOMIC_RELAXED, __HIP_MEMORY_SCOPE_AGENT);
}
__device__ __forceinline__ void astorei(int* p, int v) {
    __hip_atomic_store(p, v, __ATOMIC_RELAXED, __HIP_MEMORY_SCOPE_AGENT);
}

// Grid barrier with NO cache-wide ops: every wave drains its own vmem
// (sc1 stores complete at the coherence point => globally visible), block
// barrier, then one relaxed agent-scope arrive+spin per block.
__device__ __forceinline__ void gsync(unsigned* bar, int slot) {
    __atomic_signal_fence(__ATOMIC_SEQ_CST);
    __builtin_amdgcn_s_waitcnt(0);          // this wave's stores are ack'd
    __syncthreads();                        // => all waves in block drained
    if (threadIdx.x == 0) {
        __hip_atomic_fetch_add(&bar[slot], 1u, __ATOMIC_RELAXED, __HIP_MEMORY_SCOPE_AGENT);
        while (__hip_atomic_load(&bar[slot], __ATOMIC_RELAXED, __HIP_MEMORY_SCOPE_AGENT) < NBLK) { }
    }
    __syncthreads();
    __atomic_signal_fence(__ATOMIC_SEQ_CST);
}

// ---------------------------------------------------------------------------
__global__ __launch_bounds__(256, 1) void k_fusion(
        const float* __restrict__ chunks,
        const float* __restrict__ bw1, const float* __restrict__ bb1,
        const float* __restrict__ bw2, const float* __restrict__ bb2,
        const float* __restrict__ bw3, const float* __restrict__ bb3,
        const float* __restrict__ pw1, const float* __restrict__ pb1,
        const float* __restrict__ pw2, const float* __restrict__ pb2,
        const float* __restrict__ pw3, const float* __restrict__ pb3,
        unsigned* bar,
        float* __restrict__ fin, float* __restrict__ fused,
        int* __restrict__ jmax_all, float* __restrict__ out) {
#pragma clang fp contract(off)
    // smem union: phase A cands 2080 float4 = 8320 f  [0,8320)
    //             phase A partials u64[32][32] = 2048 f [8320,10368)
    //             phase C: W2 5120 | B2 32 | F 132 | H1 1312 | H2 1184 = 7780 f
    __shared__ __align__(16) float smem[10368];
    __shared__ int mi_lds[32];      // per-pair match indices (A' -> C, same block)
    int tid = threadIdx.x;
    int bid = blockIdx.x;
    int gidx = bid * 256 + tid;
    int slot = 0;

    // ---------------- setup: fin = chunks (sc1), jmax = -1 ----------------
    for (int i = gidx; i < NCH * NPTS * 3; i += 65536) astore(&fin[i], chunks[i]);
    if (gidx < (NCH - 1) * NPTS) astorei(&jmax_all[gidx], -1);
    gsync(bar, slot++);

    for (int pair = 1; pair < NCH; ++pair) {
        const float* C = chunks + pair * NPTS * 3;
        float* P  = fin + (pair - 1) * NPTS * 3;
        float* Pn = fin + pair * NPTS * 3;
        int* jmax = jmax_all + (pair - 1) * NPTS;

        // ---------- phase A': per-block-complete argmin + MLP resolve ----------
        {
            float4* sh4 = (float4*)smem;
            unsigned long long* part = (unsigned long long*)(smem + 8320);
            int qg = tid & 7, sr = tid >> 3;          // 8 query-groups x 32 cand-ranges
            int qbase = bid * 32 + qg * 4;
            float q0[4], q1[4], q2[4], pp[4], best[4];
            int bk[4];
#pragma unroll
            for (int jq = 0; jq < 4; ++jq) {
                q0[jq] = aload(&P[(qbase + jq) * 3 + 0]);
                q1[jq] = aload(&P[(qbase + jq) * 3 + 1]);
                q2[jq] = aload(&P[(qbase + jq) * 3 + 2]);
                pp[jq] = (q0[jq] * q0[jq] + q1[jq] * q1[jq]) + q2[jq] * q2[jq];
                best[jq] = 3.4e38f;
                bk[jq] = 0;
            }
            for (int st = 0; st < 4; ++st) {
                // stage 2048 cands: thread loads 8 consecutive rows (6 float4s)
                {
                    int c0 = st * 2048 + tid * 8;
                    const float4* src = (const float4*)(C + c0 * 3);
                    float fx[24];
#pragma unroll
                    for (int q = 0; q < 6; ++q) {
                        float4 v = src[q];
                        fx[q * 4 + 0] = v.x; fx[q * 4 + 1] = v.y;
                        fx[q * 4 + 2] = v.z; fx[q * 4 + 3] = v.w;
                    }
                    int lbase = tid * 8 + (tid >> 3);   // pad: +1 float4 per 64 cands
#pragma unroll
                    for (int u = 0; u < 8; ++u) {
                        float x = fx[u * 3 + 0], y = fx[u * 3 + 1], z = fx[u * 3 + 2];
                        float cc = (x * x + y * y) + z * z;
                        sh4[lbase + u] = make_float4(x, y, z, cc);
                    }
                }
                __syncthreads();
                int base4 = sr * 65;
                int kab = st * 2048 + sr * 64;
#pragma unroll 4
                for (int i = 0; i < 64; ++i) {
                    float4 f = sh4[base4 + i];
                    int kk = kab + i;
#pragma unroll
                    for (int jq = 0; jq < 4; ++jq) {
                        float g = __builtin_fmaf(q2[jq], f.z,
                                  __builtin_fmaf(q1[jq], f.y, q0[jq] * f.x));
                        float sadd = pp[jq] + f.w;
                        float d = __builtin_fmaf(-2.0f, g, sadd);
                        if (d < best[jq]) { best[jq] = d; bk[jq] = kk; }  // strict <
                    }
                }
                __syncthreads();
            }
            // pack partials: (order-preserving d) << 32 | k  -> u64 min is (d,k) lex-min
#pragma unroll
            for (int jq = 0; jq < 4; ++jq) {
                unsigned ud = __float_as_uint(best[jq]);
                if (ud == 0x80000000u) ud = 0u;                        // -0 -> +0
                ud = (ud & 0x80000000u) ? ~ud : (ud | 0x80000000u);
                part[(qg * 4 + jq) * 32 + sr] =
                    ((unsigned long long)ud << 32) | (unsigned long long)(unsigned)bk[jq];
            }
            __syncthreads();

            if (tid < 32) {
                unsigned long long bb = part[tid * 32];
#pragma unroll
                for (int s = 1; s < 32; ++s) {
                    unsigned long long v = part[tid * 32 + s];
                    if (v < bb) bb = v;
                }
                int m = (int)(unsigned)(bb & 0xFFFFFFFFull);
                mi_lds[tid] = m;
                int j = bid * 32 + tid;
                float x6[6];
                x6[0] = aload(&P[j * 3 + 0]);
                x6[1] = aload(&P[j * 3 + 1]);
                x6[2] = aload(&P[j * 3 + 2]);
                x6[3] = C[m * 3 + 0]; x6[4] = C[m * 3 + 1]; x6[5] = C[m * 3 + 2];

                float h1[32];
#pragma unroll
                for (int o = 0; o < 32; ++o) {
                    float acc = 0.0f;
#pragma unroll
                    for (int ci = 0; ci < 6; ++ci) acc = __builtin_fmaf(x6[ci], pw1[o * 6 + ci], acc);
                    h1[o] = fmaxf(acc + pb1[o], 0.0f);
                }
                float h2[16];
#pragma unroll
                for (int o = 0; o < 16; ++o) {
                    float acc = 0.0f;
#pragma unroll
                    for (int ci = 0; ci < 32; ++ci) acc = __builtin_fmaf(h1[ci], pw2[o * 32 + ci], acc);
                    h2[o] = fmaxf(acc + pb2[o], 0.0f);
                }
                float acc = 0.0f;
#pragma unroll
                for (int ci = 0; ci < 16; ++ci) acc = __builtin_fmaf(h2[ci], pw3[ci], acc);
                float z = acc + pb3[0];
                float w = 1.0f / (1.0f + expf(-z));
                float omw = 1.0f - w;
#pragma unroll
                for (int e = 0; e < 3; ++e) {
                    float t1 = w * x6[e];
                    float t2 = omw * x6[3 + e];
                    astore(&fused[e * NPTS + j], t1 + t2);
                }
                // dedupe within the 32 active lanes, then one atomic per distinct m
                bool issue = true;
                for (int s = 1; s < 32; ++s) {
                    int om = __shfl_down(m, s);
                    if (tid + s < 32 && om == m) issue = false;
                }
                if (issue) atomicMax(&jmax[m], j);
            }
        }
        gsync(bar, slot++);

        // ---------- phase C: smoother + fused scatter ----------
        {
            float* W2 = smem;             // 5120
            float* B2 = smem + 5120;      // 32
            float* F  = smem + 5152;      // 3*44
            float* H1 = smem + 5284;      // 32*41
            float* H2 = smem + 6596;      // 32*37
            int BASE = bid * 32;

            for (int li = tid; li < 132; li += 256) {
                int c = li / 44, i = li % 44;
                int t = BASE - 6 + i;
                F[c * 44 + i] = (t >= 0 && t < NPTS) ? aload(&fused[c * NPTS + t]) : 0.0f;
            }
            // conflict-free W2 staging: stride-1 LDS writes, L1-hot gathered reads
            for (int o = tid; o < 5120; o += 256) {
                int co = o & 31, r = o >> 5;          // r = ci*5 + k
                int ci = r / 5, k = r - ci * 5;
                W2[o] = bw2[(co * 32 + ci) * 5 + k];
            }
            if (tid < 32) B2[tid] = bb2[tid];
            __syncthreads();

            {   // conv1 -> H1 on [BASE-4, BASE+36)
                int co = tid >> 3, pg = tid & 7;
                float wr[15];
#pragma unroll
                for (int q = 0; q < 15; ++q) wr[q] = bw1[co * 15 + q];
                float bias = bb1[co];
#pragma unroll
                for (int s = 0; s < 5; ++s) {
                    int i = pg * 5 + s;
                    int t = BASE - 4 + i;
                    float acc = 0.0f;
#pragma unroll
                    for (int k = 0; k < 5; ++k)
#pragma unroll
                        for (int ci = 0; ci < 3; ++ci)
                            acc = __builtin_fmaf(F[ci * 44 + i + k], wr[ci * 5 + k], acc);
                    H1[co * 41 + i] = (t >= 0 && t < NPTS) ? fmaxf(acc + bias, 0.0f) : 0.0f;
                }
            }
            __syncthreads();

            {   // conv2 -> H2 on [BASE-2, BASE+34)
                int cq = tid & 7, pq = tid >> 3;
                if (pq < 18) {
                    int i2 = pq * 2;
                    int co0 = cq * 4;
                    float acc00 = 0.f, acc01 = 0.f, acc02 = 0.f, acc03 = 0.f;
                    float acc10 = 0.f, acc11 = 0.f, acc12 = 0.f, acc13 = 0.f;
                    for (int k = 0; k < 5; ++k) {
#pragma unroll
                        for (int ci = 0; ci < 32; ++ci) {
                            float in0 = H1[ci * 41 + i2 + k];
                            float in1 = H1[ci * 41 + i2 + k + 1];
                            const float4 wv = *(const float4*)&W2[(ci * 5 + k) * 32 + co0];
                            acc00 = __builtin_fmaf(in0, wv.x, acc00);
                            acc01 = __builtin_fmaf(in0, wv.y, acc01);
                            acc02 = __builtin_fmaf(in0, wv.z, acc02);
                            acc03 = __builtin_fmaf(in0, wv.w, acc03);
                            acc10 = __builtin_fmaf(in1, wv.x, acc10);
                            acc11 = __builtin_fmaf(in1, wv.y, acc11);
                            acc12 = __builtin_fmaf(in1, wv.z, acc12);
                            acc13 = __builtin_fmaf(in1, wv.w, acc13);
                        }
                    }
                    int t0 = BASE - 2 + i2, t1 = t0 + 1;
                    bool ok0 = (t0 >= 0 && t0 < NPTS), ok1 = (t1 >= 0 && t1 < NPTS);
                    H2[(co0 + 0) * 37 + i2]     = ok0 ? fmaxf(acc00 + B2[co0 + 0], 0.0f) : 0.0f;
                    H2[(co0 + 1) * 37 + i2]     = ok0 ? fmaxf(acc01 + B2[co0 + 1], 0.0f) : 0.0f;
                    H2[(co0 + 2) * 37 + i2]     = ok0 ? fmaxf(acc02 + B2[co0 + 2], 0.0f) : 0.0f;
                    H2[(co0 + 3) * 37 + i2]     = ok0 ? fmaxf(acc03 + B2[co0 + 3], 0.0f) : 0.0f;
                    H2[(co0 + 0) * 37 + i2 + 1] = ok1 ? fmaxf(acc10 + B2[co0 + 0], 0.0f) : 0.0f;
                    H2[(co0 + 1) * 37 + i2 + 1] = ok1 ? fmaxf(acc11 + B2[co0 + 1], 0.0f) : 0.0f;
                    H2[(co0 + 2) * 37 + i2 + 1] = ok1 ? fmaxf(acc12 + B2[co0 + 2], 0.0f) : 0.0f;
                    H2[(co0 + 3) * 37 + i2 + 1] = ok1 ? fmaxf(acc13 + B2[co0 + 3], 0.0f) : 0.0f;
                }
            }
            __syncthreads();

            if (tid < 96) {   // conv3 -> P (sm) + scatter winners -> Pn
                int co = tid >> 5, p = tid & 31;
                float wr[160];
                const float4* w3v = (const float4*)(bw3 + co * 160);
#pragma unroll
                for (int q = 0; q < 40; ++q) {
                    float4 v = w3v[q];
                    wr[q * 4 + 0] = v.x; wr[q * 4 + 1] = v.y;
                    wr[q * 4 + 2] = v.z; wr[q * 4 + 3] = v.w;
                }
                float acc = 0.0f;
#pragma unroll
                for (int k = 0; k < 5; ++k)
#pragma unroll
                    for (int ci = 0; ci < 32; ++ci)
                        acc = __builtin_fmaf(H2[ci * 37 + p + k], wr[ci * 5 + k], acc);
                float val = acc + bb3[co];
                int jj = BASE + p;
                astore(&P[jj * 3 + co], val);
                int kk = mi_lds[p];
                if (aloadi(&jmax[kk]) == jj) astore(&Pn[kk * 3 + co], val);
            }
        }
        gsync(bar, slot++);
    }

    // ---------------- merge ----------------
    {
        int pos = gidx;
        if (pos < TOTAL) {
            int imax = pos / STRIDE; if (imax > NCH - 1) imax = NCH - 1;
            int imin = (pos >= NPTS) ? ((pos - NPTS) / STRIDE + 1) : 0;
            float a0 = 0.0f, a1 = 0.0f, a2 = 0.0f, wsum = 0.0f;
            const float kstep = 0.9f / 1227.0f;
            for (int i = imin; i <= imax; ++i) {
                int t = pos - i * STRIDE;
                float cw;
                if (t < FADE)                cw = 0.1f + (float)t * kstep;
                else if (t >= NPTS - FADE)   cw = 1.0f - (float)(t - (NPTS - FADE)) * kstep;
                else                         cw = 1.0f;
                const float* v = fin + (i * NPTS + t) * 3;
                a0 += cw * aload(&v[0]);
                a1 += cw * aload(&v[1]);
                a2 += cw * aload(&v[2]);
                wsum += cw;
            }
            float wm = fmaxf(wsum, 1e-8f);
            out[pos * 3 + 0] = a0 / wm;
            out[pos * 3 + 1] = a1 / wm;
            out[pos * 3 + 2] = a2 / wm;
        }
    }
}

// ---------------------------------------------------------------------------
extern "C" void kernel_launch(void* const* d_in, const int* in_sizes, int n_in,
                              void* d_out, int out_size, void* d_ws, size_t ws_size,
                              hipStream_t stream) {
    const float* chunks = (const float*)d_in[0];
    const float* bs_w1 = (const float*)d_in[1];
    const float* bs_b1 = (const float*)d_in[2];
    const float* bs_w2 = (const float*)d_in[3];
    const float* bs_b2 = (const float*)d_in[4];
    const float* bs_w3 = (const float*)d_in[5];
    const float* bs_b3 = (const float*)d_in[6];
    const float* wp_w1 = (const float*)d_in[7];
    const float* wp_b1 = (const float*)d_in[8];
    const float* wp_w2 = (const float*)d_in[9];
    const float* wp_b2 = (const float*)d_in[10];
    const float* wp_w3 = (const float*)d_in[11];
    const float* wp_b3 = (const float*)d_in[12];

    unsigned* bar = (unsigned*)d_ws;                           // 32 u32
    float* fin      = (float*)((char*)d_ws + 128);             // 196608 f32
    float* fused    = fin + NCH * NPTS * 3;                    // 24576 f32
    int*   jmax_all = (int*)(fused + 3 * NPTS);                // 57344 i32
    float* out      = (float*)d_out;

    hipMemsetAsync(bar, 0, 128, stream);

    k_fusion<<<256, 256, 0, stream>>>(chunks,
        bs_w1, bs_b1, bs_w2, bs_b2, bs_w3, bs_b3,
        wp_w1, wp_b1, wp_w2, wp_b2, wp_w3, wp_b3,
        bar, fin, fused, jmax_all, out);
}